// Round 6
// baseline (593.084 us; speedup 1.0000x reference)
//
#include <hip/hip_runtime.h>

// ============================================================================
// MoE block (top-2 of 8 experts), T=8192 tokens, d=1024, h=2048.
// R10: FAT K-tile pipeline. R7-R9's thin 4-phase/K-tile structure paid a
// measured ~1550cy fixed overhead per phase (4x per K-tile) vs ~515cy MFMA.
// Here: ONE compute region per K-tile (64 MFMA/wave, ~2060cy/SIMD) pays the
// overhead once. Depth-2 prefetch + counted vmcnt(8) (never 0 mid-loop):
//   prologue: stage t0 -> buf0 (8 loads/wave), t1 -> buf1, vmcnt(8) [t0 done]
//   tile u (c=u&1):
//     R1: ds_read 24 frags from buf[c]; sched_barrier; lgkmcnt(0); s_barrier
//         (all waves' reads of buf[c] architecturally complete -> WAR safe)
//     R2: stage t(u+2) -> buf[c]; setprio(1); 64 MFMA; setprio(0);
//         vmcnt(8) [t(u+1) complete, t(u+2) in flight]; s_barrier
//   tails: u+2>=NT skip stage; u=NT-2 waits vmcnt(0); u=NT-1 no wait.
// No memory clobbers anywhere in the hot loop (R9-verified safe pattern).
// LDS chunk layout & frag mapping unchanged from verified R6-R9 (0 bank
// conflicts). XCD-bijective remap kept.
// ============================================================================

#define TOKS 8192
#define DIMD 1024
#define HID  2048
#define NE   8

#define OFF_COUNTS   0
#define OFF_OFFSETS  64
#define OFF_CURSORS  128
#define OFF_TILEOFF  192
#define OFF_TOPKI    256
#define OFF_TOPKG    (OFF_TOPKI + TOKS*2*4)
#define OFF_BLKPS    (OFF_TOPKG + TOKS*2*4)
#define OFF_ATOK     (OFF_BLKPS + 2048*NE*4)
#define OFF_AGATE    (OFF_ATOK + TOKS*2*4)
#define OFF_PINV     (OFF_AGATE + TOKS*2*4)
#define OFF_XG       (1u << 20)
#define XG_ROWS      (TOKS*2 + 256)
#define OFF_W1B      (OFF_XG  + (size_t)XG_ROWS * DIMD * 2)
#define OFF_W2B      (OFF_W1B + (size_t)NE * HID * DIMD * 2)
#define OFF_H        (OFF_W2B + (size_t)NE * DIMD * HID * 2)
#define OFF_Y        (OFF_H   + (size_t)XG_ROWS * HID * 2)

typedef __bf16 bf16x8 __attribute__((ext_vector_type(8)));
typedef float  floatx4 __attribute__((ext_vector_type(4)));

__device__ __forceinline__ float bf2f(unsigned short u) {
    return __uint_as_float(((unsigned)u) << 16);
}
__device__ __forceinline__ unsigned short f2bf(float f) {
    unsigned u = __float_as_uint(f);
    unsigned r = (u + 0x7FFFu + ((u >> 16) & 1u)) >> 16;
    return (unsigned short)r;
}

#define GLOBAL_AS(p) ((const __attribute__((address_space(1))) unsigned int*)(p))
#define LDS_AS(p)    ((__attribute__((address_space(3))) unsigned int*)(p))

// m204 bijective XCD-chunk remap: physical bid -> logical idx.
__device__ __forceinline__ int xcd_remap(int bid, int nwg) {
    int xcd = bid & 7, pos = bid >> 3;
    int q = nwg >> 3, r = nwg & 7;
    int start = (xcd < r) ? xcd * (q + 1) : r * (q + 1) + (xcd - r) * q;
    return start + pos;
}

// ---------------------------------------------------------------------------
// Both weight tensors -> bf16 in one pass.
__global__ void convert_w_kernel(const float4* __restrict__ w1,
                                 ushort4* __restrict__ w1b, int n1,
                                 const float4* __restrict__ w2,
                                 ushort4* __restrict__ w2b, int n2) {
    int i = blockIdx.x * blockDim.x + threadIdx.x;
    int stride = gridDim.x * blockDim.x;
    int ntot = n1 + n2;
    for (; i < ntot; i += stride) {
        float4 v; ushort4 o;
        if (i < n1) v = w1[i]; else v = w2[i - n1];
        o.x = f2bf(v.x); o.y = f2bf(v.y); o.z = f2bf(v.z); o.w = f2bf(v.w);
        if (i < n1) w1b[i] = o; else w2b[i - n1] = o;
    }
}

// ---------------------------------------------------------------------------
// One wave per token: logits = x[t] . rw[e], softmax over 8, top-2, gates.
__global__ __launch_bounds__(256) void router_kernel(
    const float* __restrict__ x, const float* __restrict__ rw,
    int* __restrict__ topki, float* __restrict__ topkg,
    float* __restrict__ blkps)
{
    int wave = threadIdx.x >> 6;
    int lane = threadIdx.x & 63;
    int t = blockIdx.x * 4 + wave;
    const float* xt = x + (size_t)t * DIMD;

    float acc[NE];
#pragma unroll
    for (int e = 0; e < NE; e++) acc[e] = 0.f;
    for (int i = 0; i < DIMD / 64; i++) {
        float xv = xt[lane + 64 * i];
#pragma unroll
        for (int e = 0; e < NE; e++) acc[e] += xv * rw[e * DIMD + lane + 64 * i];
    }
#pragma unroll
    for (int off = 32; off > 0; off >>= 1) {
#pragma unroll
        for (int e = 0; e < NE; e++) acc[e] += __shfl_down(acc[e], off);
    }

    __shared__ float ps[4][NE];
    if (lane == 0) {
        float m = acc[0];
#pragma unroll
        for (int e = 1; e < NE; e++) m = fmaxf(m, acc[e]);
        float ex[NE], s = 0.f;
#pragma unroll
        for (int e = 0; e < NE; e++) { ex[e] = expf(acc[e] - m); s += ex[e]; }
        float inv = 1.f / s;
#pragma unroll
        for (int e = 0; e < NE; e++) ps[wave][e] = ex[e] * inv;

        int i0 = 0; float l0 = acc[0];
#pragma unroll
        for (int e = 1; e < NE; e++) if (acc[e] > l0) { l0 = acc[e]; i0 = e; }
        int i1 = -1; float l1 = -3.4e38f;
#pragma unroll
        for (int e = 0; e < NE; e++) if (e != i0 && acc[e] > l1) { l1 = acc[e]; i1 = e; }
        float e1 = expf(l1 - l0);
        float g0 = 1.f / (1.f + e1);
        float g1 = e1 * g0;
        topki[t * 2 + 0] = i0; topki[t * 2 + 1] = i1;
        topkg[t * 2 + 0] = g0; topkg[t * 2 + 1] = g1;
    }
    __syncthreads();
    if (threadIdx.x < NE) {
        float s = ps[0][threadIdx.x] + ps[1][threadIdx.x] + ps[2][threadIdx.x] + ps[3][threadIdx.x];
        blkps[blockIdx.x * NE + threadIdx.x] = s;
    }
}

// ---------------------------------------------------------------------------
// Single block: counts, offsets, cursors, 256-row tile prefix, aux loss.
__global__ __launch_bounds__(256) void finalize_kernel(
    const int* __restrict__ topki, const float* __restrict__ blkps,
    int* __restrict__ counts, int* __restrict__ offsets, int* __restrict__ cursors,
    int* __restrict__ tileoff, float* __restrict__ aux_out)
{
    __shared__ float psum[NE];
    __shared__ int cnt[NE];
    int tid = threadIdx.x;
    if (tid < NE) { psum[tid] = 0.f; cnt[tid] = 0; }
    __syncthreads();

    float lp[NE]; int lc[NE];
#pragma unroll
    for (int e = 0; e < NE; e++) { lp[e] = 0.f; lc[e] = 0; }
    const float4* bp4 = (const float4*)blkps;
    for (int i = tid; i < 2048 * NE / 4; i += 256) {
        float4 v = bp4[i];
        int eb = (4 * i) & 7;   // 0 or 4
        lp[eb + 0] += v.x; lp[eb + 1] += v.y; lp[eb + 2] += v.z; lp[eb + 3] += v.w;
    }
    const int4* ti4 = (const int4*)topki;
    for (int i = tid; i < TOKS * 2 / 4; i += 256) {
        int4 v = ti4[i];
        lc[v.x]++; lc[v.y]++; lc[v.z]++; lc[v.w]++;
    }
#pragma unroll
    for (int e = 0; e < NE; e++) { atomicAdd(&psum[e], lp[e]); atomicAdd(&cnt[e], lc[e]); }
    __syncthreads();

    if (tid == 0) {
        int off = 0, to = 0;
        for (int e = 0; e < NE; e++) {
            counts[e] = cnt[e];
            offsets[e] = off; cursors[e] = off;
            tileoff[e] = to;
            off += cnt[e];
            to += (cnt[e] + 255) >> 8;     // 256-row tiles
        }
        offsets[NE] = off; tileoff[NE] = to;
        float aux = 0.f;
        for (int e = 0; e < NE; e++)
            aux += ((float)cnt[e] / (float)(TOKS * 2)) * (psum[e] / (float)TOKS);
        aux_out[0] = (float)NE * aux;
    }
}

// ---------------------------------------------------------------------------
// Build packed per-expert (token, gate) lists + inverse map token->position.
__global__ __launch_bounds__(64) void fill_kernel(
    const int* __restrict__ topki, const float* __restrict__ topkg,
    int* __restrict__ cursors, int* __restrict__ atok, float* __restrict__ agate,
    int* __restrict__ posinv)
{
    int lane = threadIdx.x;
    int t = blockIdx.x * 64 + lane;
    unsigned long long below = (lane == 63) ? 0x7FFFFFFFFFFFFFFFull
                                            : ((1ull << lane) - 1ull);
#pragma unroll
    for (int k = 0; k < 2; k++) {
        int e = topki[t * 2 + k];
        float g = topkg[t * 2 + k];
        for (int ee = 0; ee < NE; ee++) {
            bool pred = (e == ee);
            unsigned long long mask = __ballot(pred ? 1 : 0);
            if (mask) {
                int leader = __ffsll((unsigned long long)mask) - 1;
                int base = 0;
                if (lane == leader) base = atomicAdd(&cursors[ee], (int)__popcll(mask));
                base = __shfl(base, leader);
                if (pred) {
                    int pos = base + (int)__popcll(mask & below);
                    atok[pos] = t;
                    agate[pos] = g;
                    posinv[t * 2 + k] = pos;
                }
            }
        }
    }
}

// ---------------------------------------------------------------------------
// Gather x rows into packed assignment order, fp32 -> bf16.
__global__ __launch_bounds__(256) void gather_x_kernel(
    const float* __restrict__ x, const int* __restrict__ atok,
    ushort* __restrict__ Xg)
{
    int r = blockIdx.x;
    int tid = threadIdx.x;
    int tok = atok[r];
    float4 v = ((const float4*)(x + (size_t)tok * DIMD))[tid];
    ushort4 o;
    o.x = f2bf(v.x); o.y = f2bf(v.y); o.z = f2bf(v.z); o.w = f2bf(v.w);
    ((ushort4*)(Xg + (size_t)r * DIMD))[tid] = o;
}

// ===========================================================================
// 256x256 FAT K-tile GEMM core. LDS chunk = 16 rows x 32 k (1 KB); A chunks
// 0..31 (row-subtile s, khalf kk -> s*2+kk), B chunks 32..63. Per K-tile each
// wave stages subtiles {2w,2w+1} of BOTH A and B (8 x global_load_lds).
// ===========================================================================
template<int LD, int NT>
__device__ __forceinline__ void gemm_fat(
    const ushort* __restrict__ gApanel, const ushort* __restrict__ gBpanel,
    ushort (&lds)[2][64][512], floatx4 (&acc)[8][4],
    int lane, int wave, int wr, int wc, int l15, int quad)
{
    auto stage_tile = [&](int bsel, int u) {
#pragma unroll
        for (int t = 0; t < 2; t++) {
            int s = wave * 2 + t;
            const ushort* a0 = gApanel + (size_t)(s * 16 + l15) * LD + u * 64 + quad * 8;
            __builtin_amdgcn_global_load_lds(GLOBAL_AS(a0),
                LDS_AS(&lds[bsel][s * 2 + 0][0]), 16, 0, 0);
            __builtin_amdgcn_global_load_lds(GLOBAL_AS(a0 + 32),
                LDS_AS(&lds[bsel][s * 2 + 1][0]), 16, 0, 0);
            const ushort* b0 = gBpanel + (size_t)(s * 16 + l15) * LD + u * 64 + quad * 8;
            __builtin_amdgcn_global_load_lds(GLOBAL_AS(b0),
                LDS_AS(&lds[bsel][32 + s * 2 + 0][0]), 16, 0, 0);
            __builtin_amdgcn_global_load_lds(GLOBAL_AS(b0 + 32),
                LDS_AS(&lds[bsel][32 + s * 2 + 1][0]), 16, 0, 0);
        }
    };

#pragma unroll
    for (int i = 0; i < 8; i++)
#pragma unroll
        for (int j = 0; j < 4; j++) acc[i][j] = (floatx4){0.f, 0.f, 0.f, 0.f};

    // Prologue: depth-2 prefetch; vmcnt(8) completes tile0, tile1 in flight.
    stage_tile(0, 0);
    stage_tile(1, 1);
    asm volatile("s_waitcnt vmcnt(8)");
    __builtin_amdgcn_s_barrier();
    __builtin_amdgcn_sched_barrier(0);

    for (int u = 0; u < NT; u++) {
        const bf16x8* C = (const bf16x8*)&lds[u & 1][0][0];
        bf16x8 af[8][2], bfr[4][2];
        // ---- R1: read all frags of tile u ----
#pragma unroll
        for (int mi = 0; mi < 8; mi++) {
            af[mi][0] = C[((wr * 8 + mi) * 2 + 0) * 64 + lane];
            af[mi][1] = C[((wr * 8 + mi) * 2 + 1) * 64 + lane];
        }
#pragma unroll
        for (int nj = 0; nj < 4; nj++) {
            bfr[nj][0] = C[(32 + (wc * 4 + nj) * 2 + 0) * 64 + lane];
            bfr[nj][1] = C[(32 + (wc * 4 + nj) * 2 + 1) * 64 + lane];
        }
        __builtin_amdgcn_sched_barrier(0);     // pin reads above the drain
        asm volatile("s_waitcnt lgkmcnt(0)");  // own reads complete (WAR gate)
        __builtin_amdgcn_s_barrier();          // all waves done reading buf[c]
        __builtin_amdgcn_sched_barrier(0);
        // ---- R2: stage tile u+2 into freed buf[c], then MFMA ----
        if (u + 2 < NT) stage_tile(u & 1, u + 2);
        __builtin_amdgcn_s_setprio(1);
#pragma unroll
        for (int mi = 0; mi < 8; mi++)
#pragma unroll
            for (int nj = 0; nj < 4; nj++) {
                acc[mi][nj] = __builtin_amdgcn_mfma_f32_16x16x32_bf16(
                    af[mi][0], bfr[nj][0], acc[mi][nj], 0, 0, 0);
                acc[mi][nj] = __builtin_amdgcn_mfma_f32_16x16x32_bf16(
                    af[mi][1], bfr[nj][1], acc[mi][nj], 0, 0, 0);
            }
        __builtin_amdgcn_s_setprio(0);
        if (u + 1 < NT) {
            if (u + 2 < NT) asm volatile("s_waitcnt vmcnt(8)");   // t(u+1) done
            else            asm volatile("s_waitcnt vmcnt(0)");   // final drain
        }
        __builtin_amdgcn_s_barrier();
        __builtin_amdgcn_sched_barrier(0);     // next R1 reads stay below
    }
}

// ---------------------------------------------------------------------------
// Phase 1: H = gelu(Xg @ w1b[e]^T + b1[e]),  M=sum cnt, N=2048, K=1024.
__global__ __launch_bounds__(512, 2) void phase1_kernel(
    const ushort* __restrict__ Xg, const ushort* __restrict__ w1b,
    const float* __restrict__ b1,
    const int* __restrict__ counts, const int* __restrict__ offsets,
    const int* __restrict__ tileoff, unsigned short* __restrict__ Hbuf)
{
    const int NCOLT = HID / 256;   // 8 col tiles
    int total = tileoff[NE] * NCOLT;
    int idx = xcd_remap((int)blockIdx.x, (int)gridDim.x);
    if (idx >= total) return;
    int ct = idx & (NCOLT - 1);
    int rowt = idx / NCOLT;
    int e = 0;
    while (rowt >= tileoff[e + 1]) e++;
    int row0 = (rowt - tileoff[e]) * 256;
    int cnt = counts[e];
    int base = offsets[e];
    int colbase = ct * 256;

    __shared__ ushort lds[2][64][512];   // 128 KiB

    int tid = threadIdx.x;
    int lane = tid & 63;
    int wave = tid >> 6;
    int wr = wave >> 2, wc = wave & 3;
    int l15 = lane & 15, quad = lane >> 4;

    const ushort* gApanel = Xg + (size_t)(base + row0) * DIMD;
    const ushort* gBpanel = w1b + (size_t)e * HID * DIMD + (size_t)colbase * DIMD;

    floatx4 acc[8][4];
    gemm_fat<DIMD, DIMD / 64>(gApanel, gBpanel, lds, acc, lane, wave, wr, wc, l15, quad);

    // epilogue: bias + exact GELU, bf16 store. C/D: col=lane&15, row=quad*4+reg
    float b1v[4];
#pragma unroll
    for (int j = 0; j < 4; j++)
        b1v[j] = b1[e * HID + colbase + 64 * wc + 16 * j + l15];
#pragma unroll
    for (int i = 0; i < 8; i++) {
#pragma unroll
        for (int rr = 0; rr < 4; rr++) {
            int pr = row0 + 128 * wr + 16 * i + quad * 4 + rr;
            if (pr < cnt) {
                size_t hrow = (size_t)(base + pr) * HID;
#pragma unroll
                for (int j = 0; j < 4; j++) {
                    int col = colbase + 64 * wc + 16 * j + l15;
                    float v = acc[i][j][rr] + b1v[j];
                    v = 0.5f * v * (1.f + erff(v * 0.70710678118654752f));
                    Hbuf[hrow + col] = f2bf(v);
                }
            }
        }
    }
}

// ---------------------------------------------------------------------------
// Phase 2: Y = H @ w2b[e]^T,  M=sum cnt, N=1024, K=2048.
__global__ __launch_bounds__(512, 2) void phase2_kernel(
    const ushort* __restrict__ Hbuf, const ushort* __restrict__ w2b,
    const int* __restrict__ counts, const int* __restrict__ offsets,
    const int* __restrict__ tileoff, ushort* __restrict__ Y)
{
    const int NCOLT = DIMD / 256;  // 4 col tiles
    int total = tileoff[NE] * NCOLT;
    int idx = xcd_remap((int)blockIdx.x, (int)gridDim.x);
    if (idx >= total) return;
    int ct = idx & (NCOLT - 1);
    int rowt = idx / NCOLT;
    int e = 0;
    while (rowt >= tileoff[e + 1]) e++;
    int row0 = (rowt - tileoff[e]) * 256;
    int cnt = counts[e];
    int base = offsets[e];
    int colbase = ct * 256;

    __shared__ ushort lds[2][64][512];   // 128 KiB

    int tid = threadIdx.x;
    int lane = tid & 63;
    int wave = tid >> 6;
    int wr = wave >> 2, wc = wave & 3;
    int l15 = lane & 15, quad = lane >> 4;

    const ushort* gApanel = Hbuf + (size_t)(base + row0) * HID;
    const ushort* gBpanel = w2b + (size_t)e * DIMD * HID + (size_t)colbase * HID;

    floatx4 acc[8][4];
    gemm_fat<HID, HID / 64>(gApanel, gBpanel, lds, acc, lane, wave, wr, wc, l15, quad);

    // epilogue: plain bf16 store (bias+gate applied in combine)
#pragma unroll
    for (int i = 0; i < 8; i++) {
#pragma unroll
        for (int rr = 0; rr < 4; rr++) {
            int pr = row0 + 128 * wr + 16 * i + quad * 4 + rr;
            if (pr < cnt) {
                size_t yrow = (size_t)(base + pr) * DIMD;
#pragma unroll
                for (int j = 0; j < 4; j++) {
                    int col = colbase + 64 * wc + 16 * j + l15;
                    Y[yrow + col] = f2bf(acc[i][j][rr]);
                }
            }
        }
    }
}

// ---------------------------------------------------------------------------
// Combine: out[t,:] = g0*(Y[p0,:]+b2[e0,:]) + g1*(Y[p1,:]+b2[e1,:]).
__global__ __launch_bounds__(256) void combine_kernel(
    const ushort* __restrict__ Y, const float* __restrict__ b2,
    const int* __restrict__ topki, const float* __restrict__ topkg,
    const int* __restrict__ posinv, float* __restrict__ out)
{
    int wave = threadIdx.x >> 6;
    int lane = threadIdx.x & 63;
    int t = blockIdx.x * 4 + wave;
    int e0 = topki[t * 2 + 0], e1 = topki[t * 2 + 1];
    float g0 = topkg[t * 2 + 0], g1 = topkg[t * 2 + 1];
    int p0 = posinv[t * 2 + 0], p1 = posinv[t * 2 + 1];

    const ushort4* y0 = (const ushort4*)(Y + (size_t)p0 * DIMD);
    const ushort4* y1 = (const ushort4*)(Y + (size_t)p1 * DIMD);
    const float4* b20 = (const float4*)(b2 + (size_t)e0 * DIMD);
    const float4* b21 = (const float4*)(b2 + (size_t)e1 * DIMD);
    float4* o4 = (float4*)(out + (size_t)t * DIMD);

#pragma unroll
    for (int c = 0; c < DIMD / 4 / 64; c++) {   // 4 iterations
        int i = lane + 64 * c;
        ushort4 a = y0[i], b = y1[i];
        float4 ba = b20[i], bb = b21[i];
        float4 r;
        r.x = g0 * (bf2f(a.x) + ba.x) + g1 * (bf2f(b.x) + bb.x);
        r.y = g0 * (bf2f(a.y) + ba.y) + g1 * (bf2f(b.y) + bb.y);
        r.z = g0 * (bf2f(a.z) + ba.z) + g1 * (bf2f(b.z) + bb.z);
        r.w = g0 * (bf2f(a.w) + ba.w) + g1 * (bf2f(b.w) + bb.w);
        o4[i] = r;
    }
}

// ---------------------------------------------------------------------------
extern "C" void kernel_launch(void* const* d_in, const int* in_sizes, int n_in,
                              void* d_out, int out_size, void* d_ws, size_t ws_size,
                              hipStream_t stream) {
    const float* x  = (const float*)d_in[0];
    const float* rw = (const float*)d_in[1];
    const float* w1 = (const float*)d_in[2];
    const float* b1 = (const float*)d_in[3];
    const float* w2 = (const float*)d_in[4];
    const float* b2 = (const float*)d_in[5];
    float* out = (float*)d_out;

    char* ws = (char*)d_ws;
    int*   counts  = (int*)(ws + OFF_COUNTS);
    int*   offsets = (int*)(ws + OFF_OFFSETS);
    int*   cursors = (int*)(ws + OFF_CURSORS);
    int*   tileoff = (int*)(ws + OFF_TILEOFF);
    int*   topki   = (int*)(ws + OFF_TOPKI);
    float* topkg   = (float*)(ws + OFF_TOPKG);
    float* blkps   = (float*)(ws + OFF_BLKPS);
    int*   atok    = (int*)(ws + OFF_ATOK);
    float* agate   = (float*)(ws + OFF_AGATE);
    int*   posinv  = (int*)(ws + OFF_PINV);
    ushort* Xg     = (ushort*)(ws + OFF_XG);
    ushort* w1b    = (ushort*)(ws + OFF_W1B);
    ushort* w2b    = (ushort*)(ws + OFF_W2B);
    ushort* Hbuf   = (ushort*)(ws + OFF_H);
    ushort* Y      = (ushort*)(ws + OFF_Y);

    // weight conversions (independent of routing), one pass
    convert_w_kernel<<<8192, 256, 0, stream>>>(
        (const float4*)w1, (ushort4*)w1b, NE * HID * DIMD / 4,
        (const float4*)w2, (ushort4*)w2b, NE * DIMD * HID / 4);

    router_kernel<<<TOKS / 4, 256, 0, stream>>>(x, rw, topki, topkg, blkps);
    finalize_kernel<<<1, 256, 0, stream>>>(topki, blkps, counts, offsets, cursors,
                                           tileoff, out + (size_t)TOKS * DIMD);
    fill_kernel<<<TOKS / 64, 64, 0, stream>>>(topki, topkg, cursors, atok, agate,
                                              posinv);
    gather_x_kernel<<<TOKS * 2, 256, 0, stream>>>(x, atok, Xg);

    // worst-case 256-row tiles: sum_e ceil(cnt_e/256) <= 16384/256 + 7 = 71
    phase1_kernel<<<71 * (HID / 256), 512, 0, stream>>>(
        Xg, w1b, b1, counts, offsets, tileoff, Hbuf);
    phase2_kernel<<<71 * (DIMD / 256), 512, 0, stream>>>(
        Hbuf, w2b, counts, offsets, tileoff, Y);
    combine_kernel<<<TOKS / 4, 256, 0, stream>>>(Y, b2, topki, topkg, posinv, out);
}

// Round 7
// 592.839 us; speedup vs baseline: 1.0004x; 1.0004x over previous
//
#include <hip/hip_runtime.h>

// ============================================================================
// MoE block (top-2 of 8 experts), T=8192 tokens, d=1024, h=2048.
// R11: OCCUPANCY. Five schedules (R6-R10) were flat at ~168-183us with
// OccupancyPercent pinned at 16% (1 block/CU): unified VGPR+AGPR file means
// acc[8][4] (128 AGPR) + 128 VGPR = 256 regs/thread -> 8 waves/CU, AND LDS
// was 128KiB. No co-resident block -> every stall is exposed (m114: TLP
// between blocks is what hides stalls in m97's 874TF kernel, not scheduling).
// New geometry: BM=256 x BN=128, BK=32, 8 waves, per-wave 64x64 out:
//   acc 4x4 (64 AGPR) + frags 32 VGPR -> ~115 regs, __launch_bounds__(512,4)
//   caps at 128 -> 16 waves/CU = 2 blocks. LDS 2x24KiB = 48KiB.
// Simple 2-barrier loop (stage next -> read frags -> 16 MFMA -> syncthreads);
// the vmcnt drain at the barrier is hidden by the OTHER resident block.
// B-slice per block drops 4MB -> 256KB (L2-resident; old 4MB B panel
// exactly filled an XCD L2 and thrashed). Finer grid (1136/568 blocks)
// smooths makespan. Gather fused: one block per token writes both packed
// rows (halves x reads, one fewer launch).
// ============================================================================

#define TOKS 8192
#define DIMD 1024
#define HID  2048
#define NE   8

#define OFF_COUNTS   0
#define OFF_OFFSETS  64
#define OFF_CURSORS  128
#define OFF_TILEOFF  192
#define OFF_TOPKI    256
#define OFF_TOPKG    (OFF_TOPKI + TOKS*2*4)
#define OFF_BLKPS    (OFF_TOPKG + TOKS*2*4)
#define OFF_ATOK     (OFF_BLKPS + 2048*NE*4)
#define OFF_AGATE    (OFF_ATOK + TOKS*2*4)
#define OFF_PINV     (OFF_AGATE + TOKS*2*4)
#define OFF_XG       (1u << 20)
#define XG_ROWS      (TOKS*2 + 256)
#define OFF_W1B      (OFF_XG  + (size_t)XG_ROWS * DIMD * 2)
#define OFF_W2B      (OFF_W1B + (size_t)NE * HID * DIMD * 2)
#define OFF_H        (OFF_W2B + (size_t)NE * DIMD * HID * 2)
#define OFF_Y        (OFF_H   + (size_t)XG_ROWS * HID * 2)

typedef __bf16 bf16x8 __attribute__((ext_vector_type(8)));
typedef float  floatx4 __attribute__((ext_vector_type(4)));

__device__ __forceinline__ float bf2f(unsigned short u) {
    return __uint_as_float(((unsigned)u) << 16);
}
__device__ __forceinline__ unsigned short f2bf(float f) {
    unsigned u = __float_as_uint(f);
    unsigned r = (u + 0x7FFFu + ((u >> 16) & 1u)) >> 16;
    return (unsigned short)r;
}

#define GLOBAL_AS(p) ((const __attribute__((address_space(1))) unsigned int*)(p))
#define LDS_AS(p)    ((__attribute__((address_space(3))) unsigned int*)(p))

// m204 bijective XCD-chunk remap: physical bid -> logical idx.
__device__ __forceinline__ int xcd_remap(int bid, int nwg) {
    int xcd = bid & 7, pos = bid >> 3;
    int q = nwg >> 3, r = nwg & 7;
    int start = (xcd < r) ? xcd * (q + 1) : r * (q + 1) + (xcd - r) * q;
    return start + pos;
}

// ---------------------------------------------------------------------------
// Both weight tensors -> bf16 in one pass.
__global__ void convert_w_kernel(const float4* __restrict__ w1,
                                 ushort4* __restrict__ w1b, int n1,
                                 const float4* __restrict__ w2,
                                 ushort4* __restrict__ w2b, int n2) {
    int i = blockIdx.x * blockDim.x + threadIdx.x;
    int stride = gridDim.x * blockDim.x;
    int ntot = n1 + n2;
    for (; i < ntot; i += stride) {
        float4 v; ushort4 o;
        if (i < n1) v = w1[i]; else v = w2[i - n1];
        o.x = f2bf(v.x); o.y = f2bf(v.y); o.z = f2bf(v.z); o.w = f2bf(v.w);
        if (i < n1) w1b[i] = o; else w2b[i - n1] = o;
    }
}

// ---------------------------------------------------------------------------
// One wave per token: logits = x[t] . rw[e], softmax over 8, top-2, gates.
__global__ __launch_bounds__(256) void router_kernel(
    const float* __restrict__ x, const float* __restrict__ rw,
    int* __restrict__ topki, float* __restrict__ topkg,
    float* __restrict__ blkps)
{
    int wave = threadIdx.x >> 6;
    int lane = threadIdx.x & 63;
    int t = blockIdx.x * 4 + wave;
    const float* xt = x + (size_t)t * DIMD;

    float acc[NE];
#pragma unroll
    for (int e = 0; e < NE; e++) acc[e] = 0.f;
    for (int i = 0; i < DIMD / 64; i++) {
        float xv = xt[lane + 64 * i];
#pragma unroll
        for (int e = 0; e < NE; e++) acc[e] += xv * rw[e * DIMD + lane + 64 * i];
    }
#pragma unroll
    for (int off = 32; off > 0; off >>= 1) {
#pragma unroll
        for (int e = 0; e < NE; e++) acc[e] += __shfl_down(acc[e], off);
    }

    __shared__ float ps[4][NE];
    if (lane == 0) {
        float m = acc[0];
#pragma unroll
        for (int e = 1; e < NE; e++) m = fmaxf(m, acc[e]);
        float ex[NE], s = 0.f;
#pragma unroll
        for (int e = 0; e < NE; e++) { ex[e] = expf(acc[e] - m); s += ex[e]; }
        float inv = 1.f / s;
#pragma unroll
        for (int e = 0; e < NE; e++) ps[wave][e] = ex[e] * inv;

        int i0 = 0; float l0 = acc[0];
#pragma unroll
        for (int e = 1; e < NE; e++) if (acc[e] > l0) { l0 = acc[e]; i0 = e; }
        int i1 = -1; float l1 = -3.4e38f;
#pragma unroll
        for (int e = 0; e < NE; e++) if (e != i0 && acc[e] > l1) { l1 = acc[e]; i1 = e; }
        float e1 = expf(l1 - l0);
        float g0 = 1.f / (1.f + e1);
        float g1 = e1 * g0;
        topki[t * 2 + 0] = i0; topki[t * 2 + 1] = i1;
        topkg[t * 2 + 0] = g0; topkg[t * 2 + 1] = g1;
    }
    __syncthreads();
    if (threadIdx.x < NE) {
        float s = ps[0][threadIdx.x] + ps[1][threadIdx.x] + ps[2][threadIdx.x] + ps[3][threadIdx.x];
        blkps[blockIdx.x * NE + threadIdx.x] = s;
    }
}

// ---------------------------------------------------------------------------
// Single block: counts, offsets, cursors, 256-row tile prefix, aux loss.
__global__ __launch_bounds__(256) void finalize_kernel(
    const int* __restrict__ topki, const float* __restrict__ blkps,
    int* __restrict__ counts, int* __restrict__ offsets, int* __restrict__ cursors,
    int* __restrict__ tileoff, float* __restrict__ aux_out)
{
    __shared__ float psum[NE];
    __shared__ int cnt[NE];
    int tid = threadIdx.x;
    if (tid < NE) { psum[tid] = 0.f; cnt[tid] = 0; }
    __syncthreads();

    float lp[NE]; int lc[NE];
#pragma unroll
    for (int e = 0; e < NE; e++) { lp[e] = 0.f; lc[e] = 0; }
    const float4* bp4 = (const float4*)blkps;
    for (int i = tid; i < 2048 * NE / 4; i += 256) {
        float4 v = bp4[i];
        int eb = (4 * i) & 7;   // 0 or 4
        lp[eb + 0] += v.x; lp[eb + 1] += v.y; lp[eb + 2] += v.z; lp[eb + 3] += v.w;
    }
    const int4* ti4 = (const int4*)topki;
    for (int i = tid; i < TOKS * 2 / 4; i += 256) {
        int4 v = ti4[i];
        lc[v.x]++; lc[v.y]++; lc[v.z]++; lc[v.w]++;
    }
#pragma unroll
    for (int e = 0; e < NE; e++) { atomicAdd(&psum[e], lp[e]); atomicAdd(&cnt[e], lc[e]); }
    __syncthreads();

    if (tid == 0) {
        int off = 0, to = 0;
        for (int e = 0; e < NE; e++) {
            counts[e] = cnt[e];
            offsets[e] = off; cursors[e] = off;
            tileoff[e] = to;
            off += cnt[e];
            to += (cnt[e] + 255) >> 8;     // 256-row tiles
        }
        offsets[NE] = off; tileoff[NE] = to;
        float aux = 0.f;
        for (int e = 0; e < NE; e++)
            aux += ((float)cnt[e] / (float)(TOKS * 2)) * (psum[e] / (float)TOKS);
        aux_out[0] = (float)NE * aux;
    }
}

// ---------------------------------------------------------------------------
// Build packed per-expert (token, gate) lists + inverse map token->position.
__global__ __launch_bounds__(64) void fill_kernel(
    const int* __restrict__ topki, const float* __restrict__ topkg,
    int* __restrict__ cursors, int* __restrict__ atok, float* __restrict__ agate,
    int* __restrict__ posinv)
{
    int lane = threadIdx.x;
    int t = blockIdx.x * 64 + lane;
    unsigned long long below = (lane == 63) ? 0x7FFFFFFFFFFFFFFFull
                                            : ((1ull << lane) - 1ull);
#pragma unroll
    for (int k = 0; k < 2; k++) {
        int e = topki[t * 2 + k];
        float g = topkg[t * 2 + k];
        for (int ee = 0; ee < NE; ee++) {
            bool pred = (e == ee);
            unsigned long long mask = __ballot(pred ? 1 : 0);
            if (mask) {
                int leader = __ffsll((unsigned long long)mask) - 1;
                int base = 0;
                if (lane == leader) base = atomicAdd(&cursors[ee], (int)__popcll(mask));
                base = __shfl(base, leader);
                if (pred) {
                    int pos = base + (int)__popcll(mask & below);
                    atok[pos] = t;
                    agate[pos] = g;
                    posinv[t * 2 + k] = pos;
                }
            }
        }
    }
}

// ---------------------------------------------------------------------------
// Gather: one block per TOKEN; read x[t] once (fp32->bf16), write BOTH
// packed rows (halves x reads vs per-assignment gather).
__global__ __launch_bounds__(256) void gather_x_kernel(
    const float* __restrict__ x, const int* __restrict__ posinv,
    ushort* __restrict__ Xg)
{
    int t = blockIdx.x;
    int tid = threadIdx.x;
    float4 v = ((const float4*)(x + (size_t)t * DIMD))[tid];
    ushort4 o;
    o.x = f2bf(v.x); o.y = f2bf(v.y); o.z = f2bf(v.z); o.w = f2bf(v.w);
    int p0 = posinv[t * 2 + 0], p1 = posinv[t * 2 + 1];
    ((ushort4*)(Xg + (size_t)p0 * DIMD))[tid] = o;
    ((ushort4*)(Xg + (size_t)p1 * DIMD))[tid] = o;
}

// ===========================================================================
// 256x128 GEMM core, BK=32, 8 waves, 2 blocks/CU.
// LDS chunk = 16 rows x 32 k (1 KB) = exactly one global_load_lds.
// A subtiles 0..15 (chunks 0-15), B subtiles 0..7 (chunks 16-23). 24 KiB/buf.
// Per tile each wave stages A subtiles {2w,2w+1} + B subtile w (3 loads).
// Wave (wr=wave>>1, wc=wave&1) owns 64x64 out: a[mi]=chunk wr*4+mi,
// b[nj]=chunk 16+wc*4+nj, 16 MFMA per tile.
// ===========================================================================
template<int LD, int NT>
__device__ __forceinline__ void gemm_tlp(
    const ushort* __restrict__ gApanel, const ushort* __restrict__ gBpanel,
    ushort (&lds)[2][24][512], floatx4 (&acc)[4][4],
    int lane, int wave, int wr, int wc, int l15, int quad)
{
    auto stage = [&](int bsel, int u) {
#pragma unroll
        for (int t = 0; t < 2; t++) {
            int s = wave * 2 + t;
            const ushort* a0 = gApanel + (size_t)(s * 16 + l15) * LD + u * 32 + quad * 8;
            __builtin_amdgcn_global_load_lds(GLOBAL_AS(a0),
                LDS_AS(&lds[bsel][s][0]), 16, 0, 0);
        }
        const ushort* b0 = gBpanel + (size_t)(wave * 16 + l15) * LD + u * 32 + quad * 8;
        __builtin_amdgcn_global_load_lds(GLOBAL_AS(b0),
            LDS_AS(&lds[bsel][16 + wave][0]), 16, 0, 0);
    };

#pragma unroll
    for (int i = 0; i < 4; i++)
#pragma unroll
        for (int j = 0; j < 4; j++) acc[i][j] = (floatx4){0.f, 0.f, 0.f, 0.f};

    stage(0, 0);
    __syncthreads();

    for (int u = 0; u < NT; u++) {
        if (u + 1 < NT) stage((u + 1) & 1, u + 1);   // prefetch under compute
        const bf16x8* C = (const bf16x8*)&lds[u & 1][0][0];
        bf16x8 a[4], b[4];
#pragma unroll
        for (int mi = 0; mi < 4; mi++) a[mi] = C[(wr * 4 + mi) * 64 + lane];
#pragma unroll
        for (int nj = 0; nj < 4; nj++) b[nj] = C[(16 + wc * 4 + nj) * 64 + lane];
#pragma unroll
        for (int mi = 0; mi < 4; mi++)
#pragma unroll
            for (int nj = 0; nj < 4; nj++)
                acc[mi][nj] = __builtin_amdgcn_mfma_f32_16x16x32_bf16(
                    a[mi], b[nj], acc[mi][nj], 0, 0, 0);
        __syncthreads();   // drains prefetch + guards WAR; other block hides it
    }
}

// ---------------------------------------------------------------------------
// Phase 1: H = gelu(Xg @ w1b[e]^T + b1[e]),  M=sum cnt, N=2048, K=1024.
__global__ __launch_bounds__(512, 4) void phase1_kernel(
    const ushort* __restrict__ Xg, const ushort* __restrict__ w1b,
    const float* __restrict__ b1,
    const int* __restrict__ counts, const int* __restrict__ offsets,
    const int* __restrict__ tileoff, unsigned short* __restrict__ Hbuf)
{
    const int NCOLT = HID / 128;   // 16 col tiles
    int total = tileoff[NE] * NCOLT;
    int idx = xcd_remap((int)blockIdx.x, (int)gridDim.x);
    if (idx >= total) return;
    int ct = idx & (NCOLT - 1);
    int rowt = idx / NCOLT;
    int e = 0;
    while (rowt >= tileoff[e + 1]) e++;
    int row0 = (rowt - tileoff[e]) * 256;
    int cnt = counts[e];
    int base = offsets[e];
    int colbase = ct * 128;

    __shared__ ushort lds[2][24][512];   // 48 KiB

    int tid = threadIdx.x;
    int lane = tid & 63;
    int wave = tid >> 6;
    int wr = wave >> 1, wc = wave & 1;
    int l15 = lane & 15, quad = lane >> 4;

    const ushort* gApanel = Xg + (size_t)(base + row0) * DIMD;
    const ushort* gBpanel = w1b + (size_t)e * HID * DIMD + (size_t)colbase * DIMD;

    floatx4 acc[4][4];
    gemm_tlp<DIMD, DIMD / 32>(gApanel, gBpanel, lds, acc, lane, wave, wr, wc, l15, quad);

    // epilogue: bias + exact GELU, bf16 store. C/D: col=lane&15, row=quad*4+reg
    float b1v[4];
#pragma unroll
    for (int j = 0; j < 4; j++)
        b1v[j] = b1[e * HID + colbase + 64 * wc + 16 * j + l15];
#pragma unroll
    for (int i = 0; i < 4; i++) {
#pragma unroll
        for (int rr = 0; rr < 4; rr++) {
            int pr = row0 + 64 * wr + 16 * i + quad * 4 + rr;
            if (pr < cnt) {
                size_t hrow = (size_t)(base + pr) * HID;
#pragma unroll
                for (int j = 0; j < 4; j++) {
                    int col = colbase + 64 * wc + 16 * j + l15;
                    float v = acc[i][j][rr] + b1v[j];
                    v = 0.5f * v * (1.f + erff(v * 0.70710678118654752f));
                    Hbuf[hrow + col] = f2bf(v);
                }
            }
        }
    }
}

// ---------------------------------------------------------------------------
// Phase 2: Y = H @ w2b[e]^T,  M=sum cnt, N=1024, K=2048.
__global__ __launch_bounds__(512, 4) void phase2_kernel(
    const ushort* __restrict__ Hbuf, const ushort* __restrict__ w2b,
    const int* __restrict__ counts, const int* __restrict__ offsets,
    const int* __restrict__ tileoff, ushort* __restrict__ Y)
{
    const int NCOLT = DIMD / 128;  // 8 col tiles
    int total = tileoff[NE] * NCOLT;
    int idx = xcd_remap((int)blockIdx.x, (int)gridDim.x);
    if (idx >= total) return;
    int ct = idx & (NCOLT - 1);
    int rowt = idx / NCOLT;
    int e = 0;
    while (rowt >= tileoff[e + 1]) e++;
    int row0 = (rowt - tileoff[e]) * 256;
    int cnt = counts[e];
    int base = offsets[e];
    int colbase = ct * 128;

    __shared__ ushort lds[2][24][512];   // 48 KiB

    int tid = threadIdx.x;
    int lane = tid & 63;
    int wave = tid >> 6;
    int wr = wave >> 1, wc = wave & 1;
    int l15 = lane & 15, quad = lane >> 4;

    const ushort* gApanel = Hbuf + (size_t)(base + row0) * HID;
    const ushort* gBpanel = w2b + (size_t)e * DIMD * HID + (size_t)colbase * HID;

    floatx4 acc[4][4];
    gemm_tlp<HID, HID / 32>(gApanel, gBpanel, lds, acc, lane, wave, wr, wc, l15, quad);

    // epilogue: plain bf16 store (bias+gate applied in combine)
#pragma unroll
    for (int i = 0; i < 4; i++) {
#pragma unroll
        for (int rr = 0; rr < 4; rr++) {
            int pr = row0 + 64 * wr + 16 * i + quad * 4 + rr;
            if (pr < cnt) {
                size_t yrow = (size_t)(base + pr) * DIMD;
#pragma unroll
                for (int j = 0; j < 4; j++) {
                    int col = colbase + 64 * wc + 16 * j + l15;
                    Y[yrow + col] = f2bf(acc[i][j][rr]);
                }
            }
        }
    }
}

// ---------------------------------------------------------------------------
// Combine: out[t,:] = g0*(Y[p0,:]+b2[e0,:]) + g1*(Y[p1,:]+b2[e1,:]).
__global__ __launch_bounds__(256) void combine_kernel(
    const ushort* __restrict__ Y, const float* __restrict__ b2,
    const int* __restrict__ topki, const float* __restrict__ topkg,
    const int* __restrict__ posinv, float* __restrict__ out)
{
    int wave = threadIdx.x >> 6;
    int lane = threadIdx.x & 63;
    int t = blockIdx.x * 4 + wave;
    int e0 = topki[t * 2 + 0], e1 = topki[t * 2 + 1];
    float g0 = topkg[t * 2 + 0], g1 = topkg[t * 2 + 1];
    int p0 = posinv[t * 2 + 0], p1 = posinv[t * 2 + 1];

    const ushort4* y0 = (const ushort4*)(Y + (size_t)p0 * DIMD);
    const ushort4* y1 = (const ushort4*)(Y + (size_t)p1 * DIMD);
    const float4* b20 = (const float4*)(b2 + (size_t)e0 * DIMD);
    const float4* b21 = (const float4*)(b2 + (size_t)e1 * DIMD);
    float4* o4 = (float4*)(out + (size_t)t * DIMD);

#pragma unroll
    for (int c = 0; c < DIMD / 4 / 64; c++) {   // 4 iterations
        int i = lane + 64 * c;
        ushort4 a = y0[i], b = y1[i];
        float4 ba = b20[i], bb = b21[i];
        float4 r;
        r.x = g0 * (bf2f(a.x) + ba.x) + g1 * (bf2f(b.x) + bb.x);
        r.y = g0 * (bf2f(a.y) + ba.y) + g1 * (bf2f(b.y) + bb.y);
        r.z = g0 * (bf2f(a.z) + ba.z) + g1 * (bf2f(b.z) + bb.z);
        r.w = g0 * (bf2f(a.w) + ba.w) + g1 * (bf2f(b.w) + bb.w);
        o4[i] = r;
    }
}

// ---------------------------------------------------------------------------
extern "C" void kernel_launch(void* const* d_in, const int* in_sizes, int n_in,
                              void* d_out, int out_size, void* d_ws, size_t ws_size,
                              hipStream_t stream) {
    const float* x  = (const float*)d_in[0];
    const float* rw = (const float*)d_in[1];
    const float* w1 = (const float*)d_in[2];
    const float* b1 = (const float*)d_in[3];
    const float* w2 = (const float*)d_in[4];
    const float* b2 = (const float*)d_in[5];
    float* out = (float*)d_out;

    char* ws = (char*)d_ws;
    int*   counts  = (int*)(ws + OFF_COUNTS);
    int*   offsets = (int*)(ws + OFF_OFFSETS);
    int*   cursors = (int*)(ws + OFF_CURSORS);
    int*   tileoff = (int*)(ws + OFF_TILEOFF);
    int*   topki   = (int*)(ws + OFF_TOPKI);
    float* topkg   = (float*)(ws + OFF_TOPKG);
    float* blkps   = (float*)(ws + OFF_BLKPS);
    int*   atok    = (int*)(ws + OFF_ATOK);
    float* agate   = (float*)(ws + OFF_AGATE);
    int*   posinv  = (int*)(ws + OFF_PINV);
    ushort* Xg     = (ushort*)(ws + OFF_XG);
    ushort* w1b    = (ushort*)(ws + OFF_W1B);
    ushort* w2b    = (ushort*)(ws + OFF_W2B);
    ushort* Hbuf   = (ushort*)(ws + OFF_H);
    ushort* Y      = (ushort*)(ws + OFF_Y);

    // weight conversions (independent of routing), one pass
    convert_w_kernel<<<8192, 256, 0, stream>>>(
        (const float4*)w1, (ushort4*)w1b, NE * HID * DIMD / 4,
        (const float4*)w2, (ushort4*)w2b, NE * DIMD * HID / 4);

    router_kernel<<<TOKS / 4, 256, 0, stream>>>(x, rw, topki, topkg, blkps);
    finalize_kernel<<<1, 256, 0, stream>>>(topki, blkps, counts, offsets, cursors,
                                           tileoff, out + (size_t)TOKS * DIMD);
    fill_kernel<<<TOKS / 64, 64, 0, stream>>>(topki, topkg, cursors, atok, agate,
                                              posinv);
    gather_x_kernel<<<TOKS, 256, 0, stream>>>(x, posinv, Xg);

    // worst-case 256-row tiles: sum_e ceil(cnt_e/256) <= 16384/256 + 7 = 71
    phase1_kernel<<<71 * (HID / 128), 512, 0, stream>>>(
        Xg, w1b, b1, counts, offsets, tileoff, Hbuf);
    phase2_kernel<<<71 * (DIMD / 128), 512, 0, stream>>>(
        Hbuf, w2b, counts, offsets, tileoff, Y);
    combine_kernel<<<TOKS / 4, 256, 0, stream>>>(Y, b2, topki, topkg, posinv, out);
}